// Round 9
// baseline (242.476 us; speedup 1.0000x reference)
//
#include <hip/hip_runtime.h>

typedef __attribute__((ext_vector_type(4))) float f32x4;
typedef __attribute__((ext_vector_type(4))) int   i32x4;
typedef __attribute__((ext_vector_type(8))) int   i32x8;

#define MARGIN 0.1f
#define SC1 0x7F7F7F7F   // E8M0 scale bytes = 127 -> 2^0 = 1.0

__device__ __forceinline__ unsigned int pk4(const float4 f) {
    int u = __builtin_amdgcn_cvt_pk_fp8_f32(f.x, f.y, 0, false);
    u = __builtin_amdgcn_cvt_pk_fp8_f32(f.z, f.w, u, true);
    return (unsigned)u;
}
__device__ __forceinline__ uint4 cvtcell(const float4* r) {
    return make_uint4(pk4(r[0]), pk4(r[1]), pk4(r[2]), pk4(r[3]));
}

// Kernel 1: L2-normalize inputs -> fp8 A-frags (K=128 layout, verified R6);
// neg[b] = f32 dot(x, emb[target[b]]).
__global__ __launch_bounds__(256) void prep_kernel(
    const float* __restrict__ inputs, const float* __restrict__ emb,
    const int* __restrict__ target, unsigned char* __restrict__ x_frag,
    float* __restrict__ neg)
{
    const int t = threadIdx.x;
    const int b = blockIdx.x;
    const float2 v = *reinterpret_cast<const float2*>(inputs + (size_t)b * 512 + t * 2);
    const int tgt = target[b];
    const float2 e = *reinterpret_cast<const float2*>(emb + (size_t)tgt * 512 + t * 2);
    float ss = v.x * v.x + v.y * v.y;
    float de = v.x * e.x + v.y * e.y;
    #pragma unroll
    for (int off = 32; off; off >>= 1) {
        ss += __shfl_down(ss, off);
        de += __shfl_down(de, off);
    }
    __shared__ float s_ss[4], s_de[4];
    const int wid = t >> 6, lane = t & 63;
    if (lane == 0) { s_ss[wid] = ss; s_de[wid] = de; }
    __syncthreads();
    const float tss = s_ss[0] + s_ss[1] + s_ss[2] + s_ss[3];
    const float tde = s_de[0] + s_de[1] + s_de[2] + s_de[3];
    const float inv = 1.0f / fmaxf(sqrtf(tss), 1e-12f);
    const int pk = __builtin_amdgcn_cvt_pk_fp8_f32(v.x * inv, v.y * inv, 0, false);
    const int addr = (b >> 4) * 8192 + (t >> 6) * 2048 +
                     (((t >> 4) & 3) * 16 + (b & 15)) * 32 + ((2 * t) & 31);
    *reinterpret_cast<unsigned short*>(x_frag + addr) =
        (unsigned short)(pk & 0xffff);
    if (t == 0) neg[b] = tde * inv;
}

// Kernel 2 (fused): A (x) resident in registers; emb read as f32, converted
// to fp8 in-register (cvt_pk), ds_write'd immediately into the other half of a
// double-buffered frag-major LDS tile. ONE barrier per tile. launch_bounds
// (512,1) -> 256-reg budget (empirical cap = 256/arg2) -> no spill.
__global__ __launch_bounds__(512, 1) void gemm_fused_kernel(
    const unsigned char* __restrict__ x_frag, const float* __restrict__ emb,
    const float* __restrict__ neg, float* __restrict__ partials)
{
    __shared__ unsigned char btile[65536];        // 2 x 32 KB double buffer
    const int t = threadIdx.x;
    const int wid = t >> 6, lane = t & 63;
    const int lrow = lane & 15, g = lane >> 4;
    const int nf_w = wid & 3, h_w = wid >> 2;     // staging role of this wave
    const int bx = blockIdx.x;
    const int group = (bx & 7) | ((bx >> 4) << 3);     // bx, bx+8 same group+XCD
    const int mhalf = (bx >> 3) & 1;
    const int cnt = (group < 80) ? 16 : 15;            // 80*16 + 48*15 = 2000

    // ---- A prologue: wave's 64 m-rows, full K=512 ----
    i32x8 areg[4][4];                                  // 128 VGPR
    #pragma unroll
    for (int mf = 0; mf < 4; ++mf) {
        const int f = mhalf * 32 + wid * 4 + mf;
        const i32x4* ap = reinterpret_cast<const i32x4*>(
            x_frag + (size_t)f * 8192 + lane * 32);
        #pragma unroll
        for (int kk = 0; kk < 4; ++kk) {
            const i32x4 lo = ap[kk * 128];
            const i32x4 hi = ap[kk * 128 + 1];
            areg[mf][kk] = __builtin_shufflevector(lo, hi, 0, 1, 2, 3, 4, 5, 6, 7);
        }
    }

    // ---- stage tile 0 (f32 -> fp8 -> LDS buf0) ----
    {
        const float4* sp0 = reinterpret_cast<const float4*>(emb) +
            ((size_t)(group * 64 + nf_w * 16 + lrow) * 128 + g * 8 + h_w * 4);
        #pragma unroll
        for (int kk = 0; kk < 4; ++kk) {
            float4 r[4];
            #pragma unroll
            for (int i = 0; i < 4; ++i) r[i] = sp0[kk * 32 + i];
            *reinterpret_cast<uint4*>(
                btile + kk * 8192 + h_w * 4096 + nf_w * 1024 + lane * 16) = cvtcell(r);
        }
    }
    __syncthreads();

    const int rbase = mhalf * 512 + wid * 64 + g * 4;
    float sum = 0.0f;

#define MFMA_KK(kk)                                                           \
    {                                                                         \
        _Pragma("unroll")                                                     \
        for (int nf = 0; nf < 4; ++nf) {                                      \
            const i32x4 lo = *reinterpret_cast<const i32x4*>(                 \
                bb + (kk) * 8192 + nf * 1024);                                \
            const i32x4 hi = *reinterpret_cast<const i32x4*>(                 \
                bb + (kk) * 8192 + nf * 1024 + 4096);                         \
            const i32x8 bfr = __builtin_shufflevector(lo, hi,                 \
                                                      0, 1, 2, 3, 4, 5, 6, 7);\
            _Pragma("unroll")                                                 \
            for (int mf = 0; mf < 4; ++mf)                                    \
                acc[mf][nf] = __builtin_amdgcn_mfma_scale_f32_16x16x128_f8f6f4(\
                    areg[mf][kk], bfr, acc[mf][nf], 0, 0, 0, SC1, 0, SC1);    \
        }                                                                     \
    }
#define LOADQ(dst, q)                                                         \
    {                                                                         \
        _Pragma("unroll")                                                     \
        for (int i = 0; i < 4; ++i) dst[i] = spn[(q) * 32 + i];               \
    }
// write quarter q of next tile (to buf[(j+1)&1]) -- race-free anywhere in iter j
#define WRITEQ(src, q)                                                        \
    *reinterpret_cast<uint4*>(btile + ((j + 1) & 1) * 32768 + (q) * 8192 +    \
                              h_w * 4096 + nf_w * 1024 + lane * 16) = cvtcell(src);

    #pragma unroll 1
    for (int j = 0; j < cnt; ++j) {
        const bool more = (j + 1 < cnt);
        const float4* spn = reinterpret_cast<const float4*>(emb) +
            ((size_t)((group + 128 * (j + 1)) * 64 + nf_w * 16 + lrow) * 128 +
             g * 8 + h_w * 4);

        f32x4 acc[4][4];
        #pragma unroll
        for (int i = 0; i < 4; ++i)
            #pragma unroll
            for (int k = 0; k < 4; ++k) acc[i][k] = (f32x4)(0.0f);

        const unsigned char* bb = btile + (j & 1) * 32768 + lane * 16;

        float4 ra[4], rb[4];
        if (more) { LOADQ(ra, 0); LOADQ(rb, 1); }     // 2 quarters in flight
        MFMA_KK(0);
        if (more) { WRITEQ(ra, 0); LOADQ(ra, 2); }    // cvt+write, reuse regs
        MFMA_KK(1);
        if (more) { WRITEQ(rb, 1); LOADQ(rb, 3); }
        MFMA_KK(2);
        if (more) { WRITEQ(ra, 2); }
        MFMA_KK(3);
        if (more) { WRITEQ(rb, 3); }

        // ---- fused epilogue: relu(margin + dot - neg[m]) summed ----
        #pragma unroll
        for (int mf = 0; mf < 4; ++mf) {
            const float4 nv = *reinterpret_cast<const float4*>(neg + rbase + mf * 16);
            #pragma unroll
            for (int jj = 0; jj < 4; ++jj) {
                const float thr = (&nv.x)[jj] - MARGIN;
                #pragma unroll
                for (int nf = 0; nf < 4; ++nf)
                    sum += fmaxf(acc[mf][nf][jj] - thr, 0.0f);
            }
        }

        __syncthreads();          // next-tile writes done + this-tile reads done
    }

    // ---- block reduction ----
    #pragma unroll
    for (int off = 32; off; off >>= 1) sum += __shfl_down(sum, off);
    float* red = reinterpret_cast<float*>(btile);
    if (lane == 0) red[wid] = sum;
    __syncthreads();
    if (t == 0) {
        float tot = 0.f;
        #pragma unroll
        for (int w = 0; w < 8; ++w) tot += red[w];
        partials[bx] = tot;
    }
}

// Kernel 3: deterministic final reduction of 256 block partials, mean over B.
__global__ __launch_bounds__(256) void reduce_kernel(
    const float* __restrict__ partials, float* __restrict__ out)
{
    float s = partials[threadIdx.x];
    #pragma unroll
    for (int off = 32; off; off >>= 1) s += __shfl_down(s, off);
    __shared__ float red[4];
    const int wid = threadIdx.x >> 6, lane = threadIdx.x & 63;
    if (lane == 0) red[wid] = s;
    __syncthreads();
    if (threadIdx.x == 0)
        out[0] = (red[0] + red[1] + red[2] + red[3]) * (1.0f / 1024.0f);
}

extern "C" void kernel_launch(void* const* d_in, const int* in_sizes, int n_in,
                              void* d_out, int out_size, void* d_ws, size_t ws_size,
                              hipStream_t stream)
{
    const float* inputs = (const float*)d_in[0];
    const float* emb    = (const float*)d_in[1];
    const int*   target = (const int*)d_in[2];
    float* out = (float*)d_out;
    char*  ws  = (char*)d_ws;

    unsigned char* x_frag = (unsigned char*)ws;                     // 512 KB
    float*         neg    = (float*)(ws + 524288);                  // 4 KB
    float*         parts  = (float*)(ws + 528384);                  // 1 KB

    prep_kernel<<<1024, 256, 0, stream>>>(inputs, emb, target, x_frag, neg);
    gemm_fused_kernel<<<256, 512, 0, stream>>>(x_frag, emb, neg, parts);
    reduce_kernel<<<1, 256, 0, stream>>>(parts, out);
}

// Round 10
// 97.245 us; speedup vs baseline: 2.4935x; 2.4935x over previous
//
#include <hip/hip_runtime.h>

typedef __attribute__((ext_vector_type(4))) float f32x4;
typedef __attribute__((ext_vector_type(4))) int   i32x4;
typedef __attribute__((ext_vector_type(8))) int   i32x8;

#define MARGIN 0.1f
#define SC1 0x7F7F7F7F            // E8M0 unit scale (2^0) for all 32-blocks
#define INV_SCALE (1.0f/2048.0f)  // undo x*32 and e*64 pre-scaling

// fp4 e2m1 quantizer: grid {0,.5,1,1.5,2,3,4,6}, threshold rounding, sign bit3
__device__ __forceinline__ unsigned int nib4(float a) {
    const float m = fabsf(a);
    unsigned int c = (unsigned)(m > 0.25f) + (m > 0.75f) + (m > 1.25f) +
                     (m > 1.75f) + (m > 2.5f) + (m > 3.5f) + (m > 5.0f);
    return c | ((__builtin_bit_cast(unsigned int, a) >> 28) & 8u);
}
__device__ __forceinline__ unsigned int pack8(const float4 f0, const float4 f1,
                                              float s) {
    return  nib4(f0.x * s)         | (nib4(f0.y * s) << 4)  |
           (nib4(f0.z * s) << 8)   | (nib4(f0.w * s) << 12) |
           (nib4(f1.x * s) << 16)  | (nib4(f1.y * s) << 20) |
           (nib4(f1.z * s) << 24)  | (nib4(f1.w * s) << 28);
}
__device__ __forceinline__ i32x8 pad8(const i32x4 v) {
    return (i32x8){v[0], v[1], v[2], v[3], 0, 0, 0, 0};
}

// Kernel 1 (fused): blocks 0..1999 convert emb f32 -> fp4(e*64), frag-major
// K=128 tiles (byte = tile*16384 + kk*4096 + nf*1024 + lane*16; lane&15=row,
// lane>>4=k-group of 32, nibbles k-ascending low-first). Blocks 2000..3023:
// L2-normalize inputs -> fp4(x*32) A-frags; neg[b] = exact f32 dot.
__global__ __launch_bounds__(256) void prep_convert_kernel(
    const float* __restrict__ inputs, const float* __restrict__ emb,
    const int* __restrict__ target, unsigned char* __restrict__ x_frag4,
    float* __restrict__ neg, unsigned char* __restrict__ emb4)
{
    const int t = threadIdx.x;
    __shared__ float s_ss[4], s_de[4];
    if (blockIdx.x < 2000) {
        const int nt = blockIdx.x;
        const int lane6 = t & 63, nf = t >> 6;
        const int lrow = lane6 & 15, g = lane6 >> 4;
        const float* src = emb + (size_t)(nt * 64 + nf * 16 + lrow) * 512 + g * 32;
        unsigned char* dst = emb4 + (size_t)nt * 16384 + nf * 1024 + lane6 * 16;
        #pragma unroll
        for (int kk = 0; kk < 4; ++kk) {
            const float4* s4 = reinterpret_cast<const float4*>(src + kk * 128);
            unsigned int w[4];
            #pragma unroll
            for (int d = 0; d < 4; ++d)
                w[d] = pack8(s4[2 * d], s4[2 * d + 1], 64.0f);
            *reinterpret_cast<uint4*>(dst + kk * 4096) =
                make_uint4(w[0], w[1], w[2], w[3]);
        }
    } else {
        const int b = blockIdx.x - 2000;
        const float2 v = *reinterpret_cast<const float2*>(inputs + (size_t)b * 512 + t * 2);
        const int tgt = target[b];
        const float2 e = *reinterpret_cast<const float2*>(emb + (size_t)tgt * 512 + t * 2);
        float ss = v.x * v.x + v.y * v.y;
        float de = v.x * e.x + v.y * e.y;
        #pragma unroll
        for (int off = 32; off; off >>= 1) {
            ss += __shfl_down(ss, off);
            de += __shfl_down(de, off);
        }
        const int wid = t >> 6, lane = t & 63;
        if (lane == 0) { s_ss[wid] = ss; s_de[wid] = de; }
        __syncthreads();
        const float tss = s_ss[0] + s_ss[1] + s_ss[2] + s_ss[3];
        const float tde = s_de[0] + s_de[1] + s_de[2] + s_de[3];
        const float inv = 1.0f / fmaxf(sqrtf(tss), 1e-12f);
        const float sc = inv * 32.0f;
        // A-frag fp4: frag f=b>>4, kk=t>>6, g=(t>>4)&3, byte index t&15
        const int addr = (b >> 4) * 4096 + (t >> 6) * 1024 +
                         ((((t >> 4) & 3) * 16 + (b & 15)) * 16) + (t & 15);
        x_frag4[addr] = (unsigned char)(nib4(v.x * sc) | (nib4(v.y * sc) << 4));
        if (t == 0) neg[b] = tde * inv;
    }
}

__device__ __forceinline__ void gload_lds16(const void* g, void* l) {
    __builtin_amdgcn_global_load_lds(
        (const __attribute__((address_space(1))) unsigned int*)g,
        (__attribute__((address_space(3))) unsigned int*)l, 16, 0, 0);
}

// Kernel 2: A fp4 in registers (64 VGPR), emb fp4 tiles (16 KB) streamed
// through double-buffered 32 KB LDS via global_load_lds + counted vmcnt(2).
// MX MFMA 16x16x128 f8f6f4, cbsz=blgp=4 (fp4), unit scales.
__global__ __launch_bounds__(512) void gemm_fp4_kernel(
    const unsigned char* __restrict__ x_frag4, const unsigned char* __restrict__ emb4,
    const float* __restrict__ neg, float* __restrict__ partials)
{
    __shared__ unsigned char btile[32768];        // 2 x 16 KB double buffer
    const int t = threadIdx.x;
    const int wid = t >> 6, lane = t & 63;
    const int g = lane >> 4;
    const int bx = blockIdx.x;
    const int group = (bx & 7) | ((bx >> 4) << 3);     // bx, bx+8 same group+XCD
    const int mhalf = (bx >> 3) & 1;
    const int cnt = (group < 80) ? 16 : 15;            // 80*16 + 48*15 = 2000

    // ---- A prologue: wave's 64 m-rows, full K=512, fp4 = 64 VGPR ----
    i32x4 areg[4][4];
    #pragma unroll
    for (int mf = 0; mf < 4; ++mf) {
        const int f = mhalf * 32 + wid * 4 + mf;
        #pragma unroll
        for (int kk = 0; kk < 4; ++kk)
            areg[mf][kk] = *reinterpret_cast<const i32x4*>(
                x_frag4 + (size_t)f * 4096 + kk * 1024 + lane * 16);
    }

#define STAGE(buf, tile)                                                      \
    {                                                                         \
        const size_t gb = (size_t)(tile) * 16384 + t * 16;                    \
        gload_lds16(emb4 + gb,        &btile[(buf) * 16384 + t * 16]);        \
        gload_lds16(emb4 + gb + 8192, &btile[(buf) * 16384 + t * 16 + 8192]); \
    }

    STAGE(0, group);                                   // tile j=0 (2 loads)
    float sum = 0.0f;

    #pragma unroll 1
    for (int j = 0; j < cnt; ++j) {
        if (j + 1 < cnt) {
            STAGE((j + 1) & 1, group + 128 * (j + 1));
            asm volatile("s_waitcnt vmcnt(2)" ::: "memory");
        } else {
            asm volatile("s_waitcnt vmcnt(0)" ::: "memory");
        }
        __builtin_amdgcn_s_barrier();                  // tile j staged for all
        __builtin_amdgcn_sched_barrier(0);

        f32x4 acc[4][4];
        #pragma unroll
        for (int i = 0; i < 4; ++i)
            #pragma unroll
            for (int k = 0; k < 4; ++k) acc[i][k] = (f32x4)(0.0f);

        const unsigned char* bb = btile + (j & 1) * 16384 + lane * 16;
        #pragma unroll
        for (int kk = 0; kk < 4; ++kk) {
            #pragma unroll
            for (int nf = 0; nf < 4; ++nf) {
                const i32x4 b4 = *reinterpret_cast<const i32x4*>(
                    bb + kk * 4096 + nf * 1024);
                const i32x8 b8 = pad8(b4);
                #pragma unroll
                for (int mf = 0; mf < 4; ++mf)
                    acc[mf][nf] = __builtin_amdgcn_mfma_scale_f32_16x16x128_f8f6f4(
                        pad8(areg[mf][kk]), b8, acc[mf][nf],
                        4, 4, 0, SC1, 0, SC1);         // cbsz=4 (fp4 A), blgp=4 (fp4 B)
            }
        }

        // ---- fused epilogue: relu(margin + dot - neg[m]) summed ----
        const int rbase = mhalf * 512 + wid * 64 + g * 4;
        #pragma unroll
        for (int mf = 0; mf < 4; ++mf) {
            const float4 nv = *reinterpret_cast<const float4*>(neg + rbase + mf * 16);
            #pragma unroll
            for (int jj = 0; jj < 4; ++jj) {
                const float thr = (&nv.x)[jj] - MARGIN;
                #pragma unroll
                for (int nf = 0; nf < 4; ++nf)
                    sum += fmaxf(acc[mf][nf][jj] * INV_SCALE - thr, 0.0f);
            }
        }
        __builtin_amdgcn_sched_barrier(0);
        __builtin_amdgcn_s_barrier();                  // all done reading buf[j&1]
    }

    // ---- block reduction ----
    __syncthreads();
    #pragma unroll
    for (int off = 32; off; off >>= 1) sum += __shfl_down(sum, off);
    float* red = reinterpret_cast<float*>(btile);
    if (lane == 0) red[wid] = sum;
    __syncthreads();
    if (t == 0) {
        float tot = 0.f;
        #pragma unroll
        for (int w = 0; w < 8; ++w) tot += red[w];
        partials[bx] = tot;
    }
}

// Kernel 3: deterministic final reduction of 256 block partials, mean over B.
__global__ __launch_bounds__(256) void reduce_kernel(
    const float* __restrict__ partials, float* __restrict__ out)
{
    float s = partials[threadIdx.x];
    #pragma unroll
    for (int off = 32; off; off >>= 1) s += __shfl_down(s, off);
    __shared__ float red[4];
    const int wid = threadIdx.x >> 6, lane = threadIdx.x & 63;
    if (lane == 0) red[wid] = s;
    __syncthreads();
    if (threadIdx.x == 0)
        out[0] = (red[0] + red[1] + red[2] + red[3]) * (1.0f / 1024.0f);
}

extern "C" void kernel_launch(void* const* d_in, const int* in_sizes, int n_in,
                              void* d_out, int out_size, void* d_ws, size_t ws_size,
                              hipStream_t stream)
{
    const float* inputs = (const float*)d_in[0];
    const float* emb    = (const float*)d_in[1];
    const int*   target = (const int*)d_in[2];
    float* out = (float*)d_out;
    char*  ws  = (char*)d_ws;

    unsigned char* x_frag4 = (unsigned char*)ws;                    // 256 KB
    float*         neg     = (float*)(ws + 262144);                 // 4 KB
    float*         parts   = (float*)(ws + 266240);                 // 1 KB
    unsigned char* emb4    = (unsigned char*)(ws + 1048576);        // 32.8 MB

    prep_convert_kernel<<<3024, 256, 0, stream>>>(inputs, emb, target,
                                                  x_frag4, neg, emb4);
    gemm_fp4_kernel<<<256, 512, 0, stream>>>(x_frag4, emb4, neg, parts);
    reduce_kernel<<<1, 256, 0, stream>>>(parts, out);
}